// Round 1
// baseline (390.246 us; speedup 1.0000x reference)
//
#include <hip/hip_runtime.h>
#include <hip/hip_bf16.h>
#include <stdint.h>

typedef __attribute__((ext_vector_type(8))) short bf16x8;
typedef __attribute__((ext_vector_type(4))) short bf16x4v;
typedef __attribute__((ext_vector_type(4))) float f32x4;

#define B_    2
#define L_    2048
#define DIM_  2048
#define NH_   32
#define NKV_  8
#define HD_   64
#define KVD_  512          // NKV_*HD_
#define SCALE_ 0.125f
#define LOG2E 1.44269504088896f

__device__ __forceinline__ unsigned short f2bf(float f) {
  unsigned u = __float_as_uint(f);
  u += 0x7fff + ((u >> 16) & 1);          // round-to-nearest-even
  return (unsigned short)(u >> 16);
}
__device__ __forceinline__ float bf2f(unsigned short h) {
  return __uint_as_float(((unsigned)h) << 16);
}

#define GLDS16(gsrc, ldst) __builtin_amdgcn_global_load_lds( \
    (const __attribute__((address_space(1))) unsigned int*)(gsrc), \
    (__attribute__((address_space(3))) unsigned int*)(ldst), 16, 0, 0)

// ---------------- f32 -> bf16 convert (vectorized) ----------------
__global__ void cvt_kernel(const float* __restrict__ in,
                           unsigned short* __restrict__ out, int n4) {
  int i = blockIdx.x * blockDim.x + threadIdx.x;
  if (i >= n4) return;
  float4 v = reinterpret_cast<const float4*>(in)[i];
  ushort4 o;
  o.x = f2bf(v.x); o.y = f2bf(v.y); o.z = f2bf(v.z); o.w = f2bf(v.w);
  reinterpret_cast<ushort4*>(out)[i] = o;
}

// ---------------- GEMM: C[M,N] = A[M,K] * W[N,K]^T  (bf16 in, bf16/f32 out)
// m97 structure: 128x128 tile, BK=64, 4 waves (2x2), 4x4 16x16x32 frags/wave
template<int OUT_F32>
__global__ __launch_bounds__(256) void gemm_bt(
    const unsigned short* __restrict__ A,
    const unsigned short* __restrict__ W,
    void* __restrict__ C, int M, int N, int K)
{
  __shared__ unsigned short As[128 * 64];
  __shared__ unsigned short Bs[128 * 64];
  const int tid = threadIdx.x;
  const int lane = tid & 63, wid = tid >> 6;
  const int wm = wid >> 1, wn = wid & 1;
  const int r = lane & 15, g = lane >> 4;
  const int m0 = blockIdx.y * 128, n0 = blockIdx.x * 128;
  f32x4 acc[4][4] = {};
  for (int k0 = 0; k0 < K; k0 += 64) {
#pragma unroll
    for (int p = 0; p < 4; ++p) {
      int off = (p * 256 + tid) * 16;
      int row = off >> 7, colb = off & 127;
      GLDS16((const char*)A + ((size_t)(m0 + row) * K + k0) * 2 + colb,
             (char*)As + off);
      GLDS16((const char*)W + ((size_t)(n0 + row) * K + k0) * 2 + colb,
             (char*)Bs + off);
    }
    __syncthreads();
#pragma unroll
    for (int kk = 0; kk < 2; ++kk) {
      bf16x8 af[4], bfv[4];
#pragma unroll
      for (int i = 0; i < 4; ++i)
        af[i] = *reinterpret_cast<const bf16x8*>(&As[(wm * 64 + i * 16 + r) * 64 + kk * 32 + g * 8]);
#pragma unroll
      for (int i = 0; i < 4; ++i)
        bfv[i] = *reinterpret_cast<const bf16x8*>(&Bs[(wn * 64 + i * 16 + r) * 64 + kk * 32 + g * 8]);
#pragma unroll
      for (int i = 0; i < 4; ++i)
#pragma unroll
        for (int j = 0; j < 4; ++j)
          acc[i][j] = __builtin_amdgcn_mfma_f32_16x16x32_bf16(af[i], bfv[j], acc[i][j], 0, 0, 0);
    }
    __syncthreads();
  }
  // C/D layout: col = lane&15, row = (lane>>4)*4 + j   [m89-verified]
#pragma unroll
  for (int i = 0; i < 4; ++i)
#pragma unroll
    for (int jf = 0; jf < 4; ++jf)
#pragma unroll
      for (int j = 0; j < 4; ++j) {
        size_t row = (size_t)(m0 + wm * 64 + i * 16 + g * 4 + j);
        size_t col = (size_t)(n0 + wn * 64 + jf * 16 + r);
        float v = acc[i][jf][j];
        if (OUT_F32) ((float*)C)[row * N + col] = v;
        else ((unsigned short*)C)[row * N + col] = f2bf(v);
      }
}

// ---------------- RoPE (in-place, pair per thread) ----------------
__global__ void rope_kernel(unsigned short* __restrict__ t,
                            const float* __restrict__ fc,
                            const float* __restrict__ fs, int rowElems) {
  int p = blockIdx.x * blockDim.x + threadIdx.x;
  int pairsPerRow = rowElems >> 1;
  int row = p / pairsPerRow;
  if (row >= B_ * L_) return;
  int pi = p - row * pairsPerRow;
  int l = row & (L_ - 1);
  int h = pi >> 5, i = pi & 31;
  size_t base = (size_t)row * rowElems + h * 64 + 2 * i;
  float te = bf2f(t[base]), to = bf2f(t[base + 1]);
  float c = fc[l * 32 + i], s = fs[l * 32 + i];
  t[base]     = f2bf(te * c - to * s);
  t[base + 1] = f2bf(te * s + to * c);
}

// ---------------- V transpose: [B*L, KVD] -> [B,KV,D,L] ----------------
__global__ void transpose_v(const unsigned short* __restrict__ V,
                            unsigned short* __restrict__ Vt) {
  __shared__ unsigned short tile[64][65];
  int bkv = blockIdx.y;
  int b = bkv >> 3, kv = bkv & 7;
  int l0 = blockIdx.x * 64;
  int t = threadIdx.x;
#pragma unroll
  for (int it = 0; it < 16; ++it) {
    int idx = it * 256 + t;
    int lr = idx >> 6, dc = idx & 63;
    tile[lr][dc] = V[((size_t)(b * L_) + l0 + lr) * KVD_ + kv * HD_ + dc];
  }
  __syncthreads();
#pragma unroll
  for (int it = 0; it < 16; ++it) {
    int idx = it * 256 + t;
    int dr = idx >> 6, lc = idx & 63;
    Vt[(((size_t)(b * NKV_ + kv)) * HD_ + dr) * L_ + l0 + lc] = tile[lc][dr];
  }
}

// ---------------- Flash attention ----------------
// grid: (L/64 q-tiles, B*H).  4 waves x 16 q-rows.  K-tile = 64.
// S^T = mfma(K, Q^T): softmax stats lane-local at q = lane&15.
// K/V LDS tiles XOR-swizzled (byte ^= (row&7)<<4) via pre-swizzled global src.
__global__ __launch_bounds__(256) void attn_kernel(
    const unsigned short* __restrict__ Q,
    const unsigned short* __restrict__ K,
    const unsigned short* __restrict__ Vt,
    unsigned short* __restrict__ AO)
{
  __shared__ unsigned short Ks[64 * 64];
  __shared__ unsigned short Vs[64 * 64];
  __shared__ unsigned short Ps[4][16 * 64];
  const int tid = threadIdx.x;
  const int lane = tid & 63, w = tid >> 6;
  const int r = lane & 15, g = lane >> 4;
  const int bh = blockIdx.y;
  const int b = bh >> 5, h = bh & 31, kv = h >> 2;
  const int q0 = blockIdx.x * 64;
  const int qw = q0 + w * 16;

  const unsigned short* qrow = Q + ((size_t)(b * L_ + qw + r)) * DIM_ + h * HD_ + g * 8;
  bf16x8 qf0 = *reinterpret_cast<const bf16x8*>(qrow);
  bf16x8 qf1 = *reinterpret_cast<const bf16x8*>(qrow + 32);

  f32x4 o[4] = {};
  float mrow = -1e30f, lrow = 0.f;
  const int nkt = q0 / 64 + 1;

  for (int kt = 0; kt < nkt; ++kt) {
    const int k0 = kt * 64;
#pragma unroll
    for (int p = 0; p < 2; ++p) {
      int off = (p * 256 + tid) * 16;
      int row = off >> 7;
      int colb = (off & 127) ^ ((row & 7) << 4);   // inverse-swizzled source
      GLDS16((const char*)K + ((size_t)(b * L_ + k0 + row)) * (KVD_ * 2) + kv * HD_ * 2 + colb,
             (char*)Ks + off);
      GLDS16((const char*)Vt + (((size_t)(b * NKV_ + kv)) * HD_ + row) * (L_ * 2) + k0 * 2 + colb,
             (char*)Vs + off);
    }
    __syncthreads();

    // S^T tiles: rows = k (16 per kk), cols = q
    float sv[16];
#pragma unroll
    for (int kk = 0; kk < 4; ++kk) {
      int krow = kk * 16 + r;
      int rb = krow * 128, sw = (krow & 7) << 4;
      bf16x8 kf0 = *reinterpret_cast<const bf16x8*>((const char*)Ks + rb + ((g * 16) ^ sw));
      bf16x8 kf1 = *reinterpret_cast<const bf16x8*>((const char*)Ks + rb + ((64 + g * 16) ^ sw));
      f32x4 st = {};
      st = __builtin_amdgcn_mfma_f32_16x16x32_bf16(kf0, qf0, st, 0, 0, 0);
      st = __builtin_amdgcn_mfma_f32_16x16x32_bf16(kf1, qf1, st, 0, 0, 0);
#pragma unroll
      for (int j = 0; j < 4; ++j) sv[kk * 4 + j] = st[j] * SCALE_;
    }
    if (kt == nkt - 1) {             // diagonal tile: causal mask
      int q = qw + r;
#pragma unroll
      for (int kk = 0; kk < 4; ++kk)
#pragma unroll
        for (int j = 0; j < 4; ++j) {
          int k = k0 + kk * 16 + g * 4 + j;
          if (k > q) sv[kk * 4 + j] = -1e30f;
        }
    }
    // online softmax (q = lane&15 is lane-local; reduce across g via xor 16/32)
    float tm = sv[0];
#pragma unroll
    for (int i = 1; i < 16; ++i) tm = fmaxf(tm, sv[i]);
    tm = fmaxf(tm, __shfl_xor(tm, 16));
    tm = fmaxf(tm, __shfl_xor(tm, 32));
    float mnew = fmaxf(mrow, tm);
    float alpha = exp2f((mrow - mnew) * LOG2E);
    float psum = 0.f;
    unsigned short pb[16];
#pragma unroll
    for (int i = 0; i < 16; ++i) {
      float e = exp2f((sv[i] - mnew) * LOG2E);
      psum += e;
      pb[i] = f2bf(e);
    }
    psum += __shfl_xor(psum, 16);
    psum += __shfl_xor(psum, 32);
    lrow = lrow * alpha + psum;
    mrow = mnew;

    // P -> LDS: P[q=r][k], swizzled same as reads
#pragma unroll
    for (int kk = 0; kk < 4; ++kk) {
      bf16x4v pk;
      pk[0] = (short)pb[kk * 4 + 0]; pk[1] = (short)pb[kk * 4 + 1];
      pk[2] = (short)pb[kk * 4 + 2]; pk[3] = (short)pb[kk * 4 + 3];
      int cb = kk * 32 + g * 8;
      *reinterpret_cast<bf16x4v*>((char*)Ps[w] + r * 128 + (cb ^ ((r & 7) << 4))) = pk;
    }
    // rescale O by alpha (broadcast from q=lane&15 to O layout q=g*4+j)
#pragma unroll
    for (int j = 0; j < 4; ++j) {
      float aj = __shfl(alpha, g * 4 + j);
#pragma unroll
      for (int dt = 0; dt < 4; ++dt) o[dt][j] *= aj;
    }
    // PV: O[q][d] += P[16x64] * V[64x64]
#pragma unroll
    for (int ks = 0; ks < 2; ++ks) {
      bf16x8 pa = *reinterpret_cast<const bf16x8*>(
          (const char*)Ps[w] + r * 128 + ((ks * 64 + g * 16) ^ ((r & 7) << 4)));
#pragma unroll
      for (int dt = 0; dt < 4; ++dt) {
        int vrow = dt * 16 + r;
        bf16x8 vb = *reinterpret_cast<const bf16x8*>(
            (const char*)Vs + vrow * 128 + ((ks * 64 + g * 16) ^ ((vrow & 7) << 4)));
        o[dt] = __builtin_amdgcn_mfma_f32_16x16x32_bf16(pa, vb, o[dt], 0, 0, 0);
      }
    }
    __syncthreads();
  }

  float inv = 1.f / lrow;
#pragma unroll
  for (int j = 0; j < 4; ++j) {
    float ij = __shfl(inv, g * 4 + j);
    size_t orow = (size_t)(b * L_ + qw + g * 4 + j) * DIM_ + h * HD_;
#pragma unroll
    for (int dt = 0; dt < 4; ++dt)
      AO[orow + dt * 16 + r] = f2bf(o[dt][j] * ij);
  }
}

extern "C" void kernel_launch(void* const* d_in, const int* in_sizes, int n_in,
                              void* d_out, int out_size, void* d_ws, size_t ws_size,
                              hipStream_t stream) {
  const float* x  = (const float*)d_in[0];
  const float* wq = (const float*)d_in[1];
  const float* wk = (const float*)d_in[2];
  const float* wv = (const float*)d_in[3];
  const float* wo = (const float*)d_in[4];
  const float* fc = (const float*)d_in[5];
  const float* fs = (const float*)d_in[6];
  // d_in[7] = mask, unused (causal computed analytically)
  float* out = (float*)d_out;

  // workspace layout (bf16 elements); total 41,943,040 shorts = 83.9 MB
  unsigned short* ws  = (unsigned short*)d_ws;
  unsigned short* xb  = ws;                 // 8388608
  unsigned short* wqb = xb  + 8388608;      // 4194304
  unsigned short* wkb = wqb + 4194304;      // 1048576
  unsigned short* wvb = wkb + 1048576;      // 1048576
  unsigned short* wob = wvb + 1048576;      // 4194304
  unsigned short* Qb  = wob + 4194304;      // 8388608
  unsigned short* Kb  = Qb  + 8388608;      // 2097152
  unsigned short* Vb  = Kb  + 2097152;      // 2097152
  unsigned short* Vtb = Vb  + 2097152;      // 2097152
  unsigned short* AOb = Vtb + 2097152;      // 8388608

  cvt_kernel<<<8192, 256, 0, stream>>>(x,  xb,  2097152);
  cvt_kernel<<<4096, 256, 0, stream>>>(wq, wqb, 1048576);
  cvt_kernel<<<1024, 256, 0, stream>>>(wk, wkb, 262144);
  cvt_kernel<<<1024, 256, 0, stream>>>(wv, wvb, 262144);
  cvt_kernel<<<4096, 256, 0, stream>>>(wo, wob, 1048576);

  gemm_bt<0><<<dim3(16, 32), 256, 0, stream>>>(xb, wqb, Qb, 4096, 2048, 2048);
  gemm_bt<0><<<dim3(4, 32),  256, 0, stream>>>(xb, wkb, Kb, 4096, 512, 2048);
  gemm_bt<0><<<dim3(4, 32),  256, 0, stream>>>(xb, wvb, Vb, 4096, 512, 2048);

  rope_kernel<<<16384, 256, 0, stream>>>(Qb, fc, fs, 2048);
  rope_kernel<<<4096,  256, 0, stream>>>(Kb, fc, fs, 512);

  transpose_v<<<dim3(32, 16), 256, 0, stream>>>(Vb, Vtb);

  attn_kernel<<<dim3(32, 64), 256, 0, stream>>>(Qb, Kb, Vtb, AOb);

  gemm_bt<1><<<dim3(16, 32), 256, 0, stream>>>(AOb, wob, out, 4096, 2048, 2048);
}